// Round 16
// baseline (435.474 us; speedup 1.0000x reference)
//
#include <hip/hip_runtime.h>
#include <hip/hip_bf16.h>
#include <math.h>
#include <stdint.h>

// Problem constants (B=2, T=1024 -> N=2048 tokens)
#define N_TOK   2048
#define C_DIM   2048
#define E_NUM   8
#define F_MOE   1408
#define F_SH    5632
#define SLOTS   4096            // N_TOK * TOPK
#define PADROWS 4608            // SLOTS + 512 slack for 256-row tile tails

typedef __bf16 bf16;
typedef __bf16 bf16x8 __attribute__((ext_vector_type(8)));
typedef __bf16 bf16x4 __attribute__((ext_vector_type(4)));
typedef float  f32x4  __attribute__((ext_vector_type(4)));

__device__ __forceinline__ f32x4 mfma16(bf16x8 a, bf16x8 b, f32x4 c) {
    return __builtin_amdgcn_mfma_f32_16x16x32_bf16(a, b, c, 0, 0, 0);
}
__device__ __forceinline__ void gload16(const void* g, void* l) {
    __builtin_amdgcn_global_load_lds(
        (const __attribute__((address_space(1))) void*)g,
        (__attribute__((address_space(3))) void*)l, 16, 0, 0);
}
#define RAWBAR()  asm volatile("s_barrier" ::: "memory")
#define VMCNT12() asm volatile("s_waitcnt vmcnt(12)" ::: "memory")
#define VMCNT8()  asm volatile("s_waitcnt vmcnt(8)" ::: "memory")
#define VMCNT4()  asm volatile("s_waitcnt vmcnt(4)" ::: "memory")
#define VMCNT0()  asm volatile("s_waitcnt vmcnt(0)" ::: "memory")

// ---------------------------------------------------------------------------
// Router (unchanged, verified)
// ---------------------------------------------------------------------------
__global__ void router_kernel(const float* __restrict__ x,
                              const float* __restrict__ gate_w,
                              const float* __restrict__ sgate_w,
                              int* __restrict__ slotexp,
                              float* __restrict__ slotp,
                              float* __restrict__ sig)
{
    const int n   = blockIdx.x;
    const int tid = threadIdx.x;            // 256 threads
    const float* xr = x + (size_t)n * C_DIM;
    const int c0 = tid * 8;

    float xv[8];
#pragma unroll
    for (int j = 0; j < 8; ++j) xv[j] = xr[c0 + j];

    float dots[9];
#pragma unroll
    for (int e = 0; e < 9; ++e) {
        const float* wr = (e < 8) ? (gate_w + (size_t)e * C_DIM) : sgate_w;
        float p = 0.f;
#pragma unroll
        for (int j = 0; j < 8; ++j) p += xv[j] * wr[c0 + j];
#pragma unroll
        for (int off = 32; off > 0; off >>= 1) p += __shfl_down(p, off);
        dots[e] = p;
    }

    __shared__ float red[4][9];
    const int wid = tid >> 6, lane = tid & 63;
    if (lane == 0) {
#pragma unroll
        for (int e = 0; e < 9; ++e) red[wid][e] = dots[e];
    }
    __syncthreads();
    if (tid == 0) {
        float l[9];
#pragma unroll
        for (int e = 0; e < 9; ++e)
            l[e] = red[0][e] + red[1][e] + red[2][e] + red[3][e];
        float mx = l[0];
#pragma unroll
        for (int e = 1; e < 8; ++e) mx = fmaxf(mx, l[e]);
        float p[8], s = 0.f;
#pragma unroll
        for (int e = 0; e < 8; ++e) { p[e] = expf(l[e] - mx); s += p[e]; }
        const float inv = 1.f / s;
#pragma unroll
        for (int e = 0; e < 8; ++e) p[e] *= inv;
        int i1 = 0;
#pragma unroll
        for (int e = 1; e < 8; ++e) if (p[e] > p[i1]) i1 = e;
        int i2 = (i1 == 0) ? 1 : 0;
#pragma unroll
        for (int e = 0; e < 8; ++e) if (e != i1 && p[e] > p[i2]) i2 = e;
        slotexp[2 * n]     = i1;  slotp[2 * n]     = p[i1];
        slotexp[2 * n + 1] = i2;  slotp[2 * n + 1] = p[i2];
        sig[n] = 1.f / (1.f + expf(-l[8]));
    }
}

// ---------------------------------------------------------------------------
// Stable scatter (unchanged, verified)
// ---------------------------------------------------------------------------
__global__ void scatter_kernel(const int* __restrict__ slotexp,
                               int* __restrict__ counts, int* __restrict__ bases,
                               int* __restrict__ pos_of, int* __restrict__ row_token)
{
    const int tid = threadIdx.x;            // 512 threads = 8 waves
    const int w = tid >> 6, lane = tid & 63;
    __shared__ int cnt[E_NUM], base[E_NUM];

    int run = 0;
    for (int s0 = 0; s0 < SLOTS; s0 += 64) {
        int e = slotexp[s0 + lane];
        unsigned long long m = __ballot(e == w);
        run += __popcll(m);
    }
    if (lane == 0) cnt[w] = run;
    __syncthreads();
    if (tid == 0) {
        int b = 0;
        for (int e = 0; e < E_NUM; ++e) { base[e] = b; b += cnt[e]; }
    }
    __syncthreads();
    run = 0;
    for (int s0 = 0; s0 < SLOTS; s0 += 64) {
        const int s = s0 + lane;
        const int e = slotexp[s];
        unsigned long long m = __ballot(e == w);
        if (e == w) {
            const unsigned long long lt = (lane == 0) ? 0ull : (~0ull >> (64 - lane));
            const int pos = base[w] + run + __popcll(m & lt);
            pos_of[s]      = pos;
            row_token[pos] = s >> 1;
        }
        run += __popcll(m);
    }
    if (lane == 0) { counts[w] = cnt[w]; bases[w] = base[w]; }
}

// ---------------------------------------------------------------------------
// ONE f32->bf16 conversion launch. 8192 elems/block, 8 outstanding 16B
// loads/thread, non-temporal (zero-reuse stream; ~5 TB/s, near roofline).
// ---------------------------------------------------------------------------
struct CvtArgs {
    const float* in[7];
    bf16*        out[7];
    int          cum[8];     // cumulative 8192-elem block counts, cum[0]=0
};

__global__ void cvt_all_kernel(CvtArgs a)
{
    int b = blockIdx.x;
    int s = 0;
#pragma unroll
    for (int k = 1; k < 7; ++k) s += (b >= a.cum[k]);
    const size_t base = (size_t)(b - a.cum[s]) * 8192;
    const float* in = a.in[s];
    bf16* out = a.out[s];
    const int t4 = threadIdx.x * 4;
    f32x4 v[8];
#pragma unroll
    for (int c = 0; c < 8; ++c)
        v[c] = __builtin_nontemporal_load((const f32x4*)(in + base + c * 1024 + t4));
#pragma unroll
    for (int c = 0; c < 8; ++c) {
        bf16x4 o;
#pragma unroll
        for (int j = 0; j < 4; ++j) o[j] = (bf16)v[c][j];
        __builtin_nontemporal_store(o, (bf16x4*)(out + base + c * 1024 + t4));
    }
}

// ---------------------------------------------------------------------------
// Gather token rows into per-expert-contiguous Xg.
// ---------------------------------------------------------------------------
__global__ void gather_kernel(const bf16* __restrict__ Xs,
                              const int* __restrict__ row_token,
                              bf16* __restrict__ Xg)
{
    const int pos = blockIdx.x;
    const int t   = row_token[pos];
    const bf16x8* s = (const bf16x8*)(Xs + (size_t)t * C_DIM);
    bf16x8*       d = (bf16x8*)(Xg + (size_t)pos * C_DIM);
    d[threadIdx.x] = s[threadIdx.x];
}

// ---------------------------------------------------------------------------
// Deep-pipelined NT GEMM body, depth-4 + FRAGMENT DOUBLE-BUFFER (this round).
// Per iteration: [vmcnt(8): half h+1 landed][barrier][read h+1 frags into the
// OTHER reg set][issue h+4][32 MFMA on half h's set]. The ds_read latency of
// half h+1 now hides under half h's MFMA cluster (~1242 cyc/CU) instead of
// being exposed on the critical path. Steady vmcnt(8); tails 8/4/0.
// Buffer-overwrite safety: issue(h+4) writes buf (h-1)%5, whose last reads
// (read h-1, iter h-2) complete one full barrier before -- SAFE.
// Five 32-KiB half-buffers (160 KiB LDS), XOR-swizzle involution, setprio:
// all verbatim from the verified round-13/15 kernel.
// ---------------------------------------------------------------------------
template<bool DUAL, int KSPLIT>
__device__ __forceinline__ void gemm_body(
    const bf16* __restrict__ A, int lda,
    const bf16* __restrict__ B1g, const bf16* __restrict__ B2g, size_t strideB,
    bf16* __restrict__ OUTh, bf16* __restrict__ OUTq, int ldo, size_t strideOut,
    int base, int cnt, int e, int yt, int nt, int kp, int K, char* lds)
{
    const int KT = (K / 64) / KSPLIT;
    const int H  = 2 * KT;                   // K=32 halves (even, >= 22)

    const int m0 = base + yt * 256;
    const int tid = threadIdx.x;
    const int w = tid >> 6, lane = tid & 63;

    // staging decode: dest linear (wave base + lane*16); content chunk at
    // slot (lane&7) of LDS row r' is (lane&7)^(r'&7), r'&7 == lane>>3
    const int l3  = lane >> 3;
    const int chS = (lane & 7) ^ l3;
    const int hiS = chS >> 2, ccS = chS & 3;
    const int rl  = w * 16 + 2 * l3 + hiS;   // tile row within 128-row group
    const size_t lda2 = (size_t)lda * 2, K2 = (size_t)K * 2;
    const size_t kpoff = (size_t)kp * KT * 128;

    const char* aSrc0 = (const char*)A + (size_t)(m0 + rl)       * lda2 + ccS * 16 + kpoff;
    const char* aSrc1 = (const char*)A + (size_t)(m0 + 128 + rl) * lda2 + ccS * 16 + kpoff;
    const bf16* B1 = B1g + (size_t)e * strideB;
    const char* bSrc0;
    const char* bSrc1;
    if constexpr (DUAL) {
        const bf16* B2 = B2g + (size_t)e * strideB;
        bSrc0 = (const char*)B1 + (size_t)(nt * 128 + rl) * K2 + ccS * 16 + kpoff;
        bSrc1 = (const char*)B2 + (size_t)(nt * 128 + rl) * K2 + ccS * 16 + kpoff;
    } else {
        bSrc0 = (const char*)B1 + (size_t)(nt * 256 + rl)       * K2 + ccS * 16 + kpoff;
        bSrc1 = (const char*)B1 + (size_t)(nt * 256 + 128 + rl) * K2 + ccS * 16 + kpoff;
    }
    char* ldsw = lds + w * 1024;             // wave-uniform LDS dest base

    auto issue = [&](int h, int buf) {       // 4 loads/wave per half
        const size_t ko = (size_t)(h >> 1) * 128 + (size_t)(h & 1) * 64;
        char* d = ldsw + buf * 32768;
        gload16(aSrc0 + ko, d);
        gload16(aSrc1 + ko, d + 8192);
        gload16(bSrc0 + ko, d + 16384);
        gload16(bSrc1 + ko, d + 24576);
    };

    // fragment read offsets (swizzled, constant across halves)
    const int wm = w >> 2, wn = w & 3;
    const int fr = lane & 15, fq = lane >> 4;
    const int chRd = (((fr & 1) << 2) | fq) ^ ((fr >> 1) & 7);
    uint32_t aOff[8], bOff[4];
#pragma unroll
    for (int m = 0; m < 8; ++m)
        aOff[m] = (uint32_t)((wm * 64 + m * 8 + (fr >> 1)) * 128 + chRd * 16);
#pragma unroll
    for (int n = 0; n < 4; ++n) {
        int rp;
        if constexpr (DUAL)
            rp = (n < 2) ? (wn * 16 + n * 8) : (64 + wn * 16 + (n - 2) * 8);
        else
            rp = wn * 32 + n * 8;
        rp += (fr >> 1);
        bOff[n] = (uint32_t)(16384 + rp * 128 + chRd * 16);
    }

    f32x4 acc[8][4] = {};

    // two named fragment sets (rule #20: static indexing only)
    bf16x8 A0[8], B0[4], A1[8], B1f[4];

    auto readfrags = [&](int buf, bf16x8 (&FA)[8], bf16x8 (&FB)[4]) {
        const char* LB = lds + buf * 32768;
#pragma unroll
        for (int n = 0; n < 4; ++n) FB[n] = *(const bf16x8*)(LB + bOff[n]);
#pragma unroll
        for (int m = 0; m < 8; ++m) FA[m] = *(const bf16x8*)(LB + aOff[m]);
    };
    auto mfmahalf = [&](bf16x8 (&FA)[8], bf16x8 (&FB)[4]) {
        __builtin_amdgcn_s_setprio(1);
#pragma unroll
        for (int m = 0; m < 8; ++m)
#pragma unroll
            for (int n = 0; n < 4; ++n)
                acc[m][n] = mfma16(FA[m], FB[n], acc[m][n]);
        __builtin_amdgcn_s_setprio(0);
    };

    // prologue: 4 halves in flight; frags(0) -> set0
    issue(0, 0); issue(1, 1); issue(2, 2); issue(3, 3);
    VMCNT12(); RAWBAR();
    readfrags(0, A0, B0);

    int rdbuf = 1, wrbuf = 4;
    // main: pairs of halves (2it, 2it+1), it = 0 .. (H-4)/2 - 1
    for (int it = 0; it < (H - 4) / 2; ++it) {
        // even half 2it: MFMA set0; prefetch frags(2it+1) -> set1
        VMCNT8(); RAWBAR();
        readfrags(rdbuf, A1, B1f); rdbuf = (rdbuf == 4) ? 0 : rdbuf + 1;
        issue(2 * it + 4, wrbuf);  wrbuf = (wrbuf == 4) ? 0 : wrbuf + 1;
        mfmahalf(A0, B0);
        // odd half 2it+1: MFMA set1; prefetch frags(2it+2) -> set0
        VMCNT8(); RAWBAR();
        readfrags(rdbuf, A0, B0); rdbuf = (rdbuf == 4) ? 0 : rdbuf + 1;
        issue(2 * it + 5, wrbuf); wrbuf = (wrbuf == 4) ? 0 : wrbuf + 1;
        mfmahalf(A1, B1f);
    }
    // tail: halves H-4 .. H-1 (frags for H-4 already in set0)
    VMCNT8(); RAWBAR();
    readfrags(rdbuf, A1, B1f); rdbuf = (rdbuf == 4) ? 0 : rdbuf + 1;
    mfmahalf(A0, B0);                        // H-4
    VMCNT4(); RAWBAR();
    readfrags(rdbuf, A0, B0); rdbuf = (rdbuf == 4) ? 0 : rdbuf + 1;
    mfmahalf(A1, B1f);                       // H-3
    VMCNT0(); RAWBAR();
    readfrags(rdbuf, A1, B1f);
    mfmahalf(A0, B0);                        // H-2
    mfmahalf(A1, B1f);                       // H-1

    // epilogue. C/D: col = lane&15 (fr), row = fq*4 + j (m89)
    const int rb0 = m0 + wm * 128;
    const int rend = base + cnt;             // first row NOT owned by this range
#pragma unroll
    for (int m = 0; m < 8; ++m) {
#pragma unroll
        for (int j = 0; j < 4; ++j) {
            const int grow = rb0 + m * 16 + fq * 4 + j;
            if (grow >= rend) continue;      // tile tail overlaps next expert
            if constexpr (DUAL) {
#pragma unroll
                for (int n = 0; n < 2; ++n) {
                    const int gcol = nt * 128 + wn * 32 + n * 16 + fr;
                    const float h1 = acc[m][n][j];
                    const float h2 = acc[m][n + 2][j];
                    OUTh[(size_t)grow * ldo + gcol] =
                        (bf16)(h1 / (1.f + expf(-h1)) * h2);
                }
            } else {
                bf16* O = OUTq + (size_t)kp * strideOut;
#pragma unroll
                for (int n = 0; n < 4; ++n) {
                    const int gcol = nt * 256 + wn * 64 + n * 16 + fr;
                    O[(size_t)grow * ldo + gcol] = (bf16)acc[m][n][j];
                }
            }
        }
    }
}

// ---------------------------------------------------------------------------
// PROJ kernels: thin wrappers over gemm_body (round-11 grids, verified).
// ---------------------------------------------------------------------------
template<bool DUAL, bool GROUPED, int KSPLIT>
__global__ __launch_bounds__(512, 1)
void gemm8(const bf16* __restrict__ A, int lda,
           const bf16* __restrict__ B1g, const bf16* __restrict__ B2g,
           size_t strideB,
           bf16* __restrict__ OUTh, bf16* __restrict__ OUTq, int ldo,
           size_t strideOut,
           const int* __restrict__ bases, const int* __restrict__ counts,
           int K)
{
    __shared__ char lds[163840];
    int e, yt, nt, kp, base, cnt;
    if constexpr (GROUPED) {
        e = blockIdx.x; yt = blockIdx.y; nt = blockIdx.z; kp = 0;
        base = bases[e]; cnt = counts[e];
        if (yt * 256 >= cnt) return;
    } else {
        nt = blockIdx.x; yt = blockIdx.y; kp = (KSPLIT > 1) ? blockIdx.z : 0;
        e = 0; base = 0; cnt = N_TOK;
    }
    gemm_body<DUAL, KSPLIT>(A, lda, B1g, B2g, strideB, OUTh, OUTq, ldo,
                            strideOut, base, cnt, e, yt, nt, kp, K, lds);
}

// ---------------------------------------------------------------------------
// FC merged: sharedfc (352 tiles) + groupedfc (1408 tiles, ~176-220 active),
// round-11 decode (verified).
// ---------------------------------------------------------------------------
#define FC0_TILES 352            // (N_TOK/256) * (F_SH/128)

__global__ __launch_bounds__(512, 1)
void gemm_fc(const bf16* __restrict__ Xs, const bf16* __restrict__ Xg,
             const bf16* __restrict__ Wsfc1, const bf16* __restrict__ Wsfc2,
             const bf16* __restrict__ Wefc1, const bf16* __restrict__ Wefc2,
             bf16* __restrict__ Hs, bf16* __restrict__ Hm,
             const int* __restrict__ bases, const int* __restrict__ counts)
{
    __shared__ char lds[163840];
    const int id = blockIdx.x;
    if (id < FC0_TILES) {
        const int nt = id % 44, yt = id / 44;        // compile-time divisor
        gemm_body<true, 1>(Xs, C_DIM, Wsfc1, Wsfc2, 0, Hs, nullptr, F_SH, 0,
                           0, N_TOK, 0, yt, nt, 0, C_DIM, lds);
    } else {
        const int lid = id - FC0_TILES;
        const int e = lid & 7, yt = (lid >> 3) & 15, nt = lid >> 7;
        const int base = bases[e], cnt = counts[e];
        if (yt * 256 >= cnt) return;
        gemm_body<true, 1>(Xg, C_DIM, Wefc1, Wefc2, (size_t)F_MOE * C_DIM,
                           Hm, nullptr, F_MOE, 0,
                           base, cnt, e, yt, nt, 0, C_DIM, lds);
    }
}

// ---------------------------------------------------------------------------
// y[n] = sig[n]*(SP0+SP1+SP2+SP3)[n] + p0*EP[pos0] + p1*EP[pos1]
// ---------------------------------------------------------------------------
__global__ void combine_kernel(const bf16* __restrict__ SP,
                               const bf16* __restrict__ EP,
                               const int* __restrict__ pos_of,
                               const float* __restrict__ slotp,
                               const float* __restrict__ sig,
                               float* __restrict__ y)
{
    const int n  = blockIdx.x;
    const int p0 = pos_of[2 * n], p1 = pos_of[2 * n + 1];
    const float w0 = slotp[2 * n], w1 = slotp[2 * n + 1], sg = sig[n];
    const size_t PS = (size_t)N_TOK * C_DIM;
    const size_t cidx = (size_t)n * C_DIM + threadIdx.x * 8;

    bf16x8 s0 = *(const bf16x8*)(SP + cidx);
    bf16x8 s1 = *(const bf16x8*)(SP + cidx + PS);
    bf16x8 s2 = *(const bf16x8*)(SP + cidx + 2 * PS);
    bf16x8 s3 = *(const bf16x8*)(SP + cidx + 3 * PS);
    bf16x8 a0 = *(const bf16x8*)(EP + (size_t)p0 * C_DIM + threadIdx.x * 8);
    bf16x8 a1 = *(const bf16x8*)(EP + (size_t)p1 * C_DIM + threadIdx.x * 8);

    float out[8];
#pragma unroll
    for (int j = 0; j < 8; ++j) {
        const float ssum = (float)s0[j] + (float)s1[j] + (float)s2[j] + (float)s3[j];
        out[j] = sg * ssum + w0 * (float)a0[j] + w1 * (float)a1[j];
    }
    f32x4 o0, o1;
#pragma unroll
    for (int j = 0; j < 4; ++j) { o0[j] = out[j]; o1[j] = out[4 + j]; }
    *(f32x4*)(y + cidx)     = o0;
    *(f32x4*)(y + cidx + 4) = o1;
}

// ---------------------------------------------------------------------------
extern "C" void kernel_launch(void* const* d_in, const int* in_sizes, int n_in,
                              void* d_out, int out_size, void* d_ws, size_t ws_size,
                              hipStream_t stream)
{
    const float* x     = (const float*)d_in[0];
    const float* gatew = (const float*)d_in[1];
    const float* efc1  = (const float*)d_in[2];
    const float* efc2  = (const float*)d_in[3];
    const float* eproj = (const float*)d_in[4];
    const float* sfc1  = (const float*)d_in[5];
    const float* sfc2  = (const float*)d_in[6];
    const float* sproj = (const float*)d_in[7];
    const float* sgate = (const float*)d_in[8];
    float* y = (float*)d_out;

    char* w = (char*)d_ws;
    size_t off = 0;
    auto take = [&](size_t bytes) {
        char* p = w + off;
        off = (off + bytes + 255) & ~(size_t)255;
        return p;
    };
    int*   counts    = (int*)  take(E_NUM * 4);
    int*   bases     = (int*)  take(E_NUM * 4);
    int*   slotexp   = (int*)  take(SLOTS * 4);
    float* slotp     = (float*)take(SLOTS * 4);
    int*   pos_of    = (int*)  take(SLOTS * 4);
    int*   row_token = (int*)  take(PADROWS * 4);
    float* sig       = (float*)take(N_TOK * 4);
    bf16*  Xs        = (bf16*) take((size_t)N_TOK   * C_DIM * 2);
    bf16*  Xg        = (bf16*) take((size_t)PADROWS * C_DIM * 2);
    bf16*  Hs        = (bf16*) take((size_t)N_TOK   * F_SH  * 2);
    bf16*  Hm        = (bf16*) take((size_t)PADROWS * F_MOE * 2);
    bf16*  SP        = (bf16*) take((size_t)4 * N_TOK * C_DIM * 2);
    bf16*  EP        = (bf16*) take((size_t)PADROWS * C_DIM * 2);
    bf16*  Wefc1     = (bf16*) take((size_t)E_NUM * F_MOE * C_DIM * 2);
    bf16*  Wefc2     = (bf16*) take((size_t)E_NUM * F_MOE * C_DIM * 2);
    bf16*  Weproj    = (bf16*) take((size_t)E_NUM * C_DIM * F_MOE * 2);
    bf16*  Wsfc1     = (bf16*) take((size_t)F_SH * C_DIM * 2);
    bf16*  Wsfc2     = (bf16*) take((size_t)F_SH * C_DIM * 2);
    bf16*  Wsproj    = (bf16*) take((size_t)C_DIM * F_SH * 2);
    (void)ws_size; (void)in_sizes; (void)n_in; (void)out_size;

    // single merged f32->bf16 pass (8192 elems/block, non-temporal)
    CvtArgs ca;
    const int nbx  = (N_TOK * C_DIM) / 8192;                 // 512
    const int nbe  = (E_NUM * F_MOE * C_DIM) / 8192;         // 2816
    const int nbs  = (F_SH * C_DIM) / 8192;                  // 1408
    ca.in[0] = x;     ca.out[0] = Xs;
    ca.in[1] = efc1;  ca.out[1] = Wefc1;
    ca.in[2] = efc2;  ca.out[2] = Wefc2;
    ca.in[3] = eproj; ca.out[3] = Weproj;
    ca.in[4] = sfc1;  ca.out[4] = Wsfc1;
    ca.in[5] = sfc2;  ca.out[5] = Wsfc2;
    ca.in[6] = sproj; ca.out[6] = Wsproj;
    ca.cum[0] = 0;
    ca.cum[1] = nbx;
    ca.cum[2] = nbx + nbe;
    ca.cum[3] = nbx + 2 * nbe;
    ca.cum[4] = nbx + 3 * nbe;
    ca.cum[5] = nbx + 3 * nbe + nbs;
    ca.cum[6] = nbx + 3 * nbe + 2 * nbs;
    ca.cum[7] = nbx + 3 * nbe + 3 * nbs;
    cvt_all_kernel<<<ca.cum[7], 256, 0, stream>>>(ca);

    router_kernel<<<N_TOK, 256, 0, stream>>>(x, gatew, sgate, slotexp, slotp, sig);
    scatter_kernel<<<1, 512, 0, stream>>>(slotexp, counts, bases, pos_of, row_token);
    gather_kernel<<<SLOTS, 256, 0, stream>>>(Xs, row_token, Xg);

    // FC merged: sharedfc (352) + groupedfc (~176-220 active) in one grid
    gemm_fc<<<FC0_TILES + E_NUM * (SLOTS / 256) * (F_MOE / 128), 512, 0, stream>>>(
        Xs, Xg, Wsfc1, Wsfc2, Wefc1, Wefc2, Hs, Hm, bases, counts);

    // shared proj, 4-way K-split bf16 partials: SP[p] = Hs @ sproj^T
    gemm8<false, false, 4><<<dim3(C_DIM / 256, N_TOK / 256, 4), 512, 0, stream>>>(
        Hs, F_SH, Wsproj, nullptr, 0, nullptr, SP, C_DIM, (size_t)N_TOK * C_DIM,
        nullptr, nullptr, F_SH);

    // MoE proj (grouped, e-fastest grid): EP = Hm @ proj_e^T (bf16)
    gemm8<false, true, 1><<<dim3(E_NUM, SLOTS / 256, C_DIM / 256), 512, 0, stream>>>(
        Hm, F_MOE, Weproj, nullptr, (size_t)C_DIM * F_MOE, nullptr, EP, C_DIM, 0,
        bases, counts, F_MOE);

    combine_kernel<<<N_TOK, 256, 0, stream>>>(SP, EP, pos_of, slotp, sig, y);
}

// Round 17
// 408.557 us; speedup vs baseline: 1.0659x; 1.0659x over previous
//
#include <hip/hip_runtime.h>
#include <hip/hip_bf16.h>
#include <math.h>
#include <stdint.h>

// Problem constants (B=2, T=1024 -> N=2048 tokens)
#define N_TOK   2048
#define C_DIM   2048
#define E_NUM   8
#define F_MOE   1408
#define F_SH    5632
#define SLOTS   4096            // N_TOK * TOPK
#define PADROWS 4608            // SLOTS + 512 slack for 256-row tile tails

typedef __bf16 bf16;
typedef __bf16 bf16x8 __attribute__((ext_vector_type(8)));
typedef __bf16 bf16x4 __attribute__((ext_vector_type(4)));
typedef float  f32x4  __attribute__((ext_vector_type(4)));

__device__ __forceinline__ f32x4 mfma16(bf16x8 a, bf16x8 b, f32x4 c) {
    return __builtin_amdgcn_mfma_f32_16x16x32_bf16(a, b, c, 0, 0, 0);
}
__device__ __forceinline__ void gload16(const void* g, void* l) {
    __builtin_amdgcn_global_load_lds(
        (const __attribute__((address_space(1))) void*)g,
        (__attribute__((address_space(3))) void*)l, 16, 0, 0);
}
#define RAWBAR()  asm volatile("s_barrier" ::: "memory")
#define VMCNT12() asm volatile("s_waitcnt vmcnt(12)" ::: "memory")
#define VMCNT8()  asm volatile("s_waitcnt vmcnt(8)" ::: "memory")
#define VMCNT4()  asm volatile("s_waitcnt vmcnt(4)" ::: "memory")
#define VMCNT0()  asm volatile("s_waitcnt vmcnt(0)" ::: "memory")

// ---------------------------------------------------------------------------
// Router (unchanged, verified)
// ---------------------------------------------------------------------------
__global__ void router_kernel(const float* __restrict__ x,
                              const float* __restrict__ gate_w,
                              const float* __restrict__ sgate_w,
                              int* __restrict__ slotexp,
                              float* __restrict__ slotp,
                              float* __restrict__ sig)
{
    const int n   = blockIdx.x;
    const int tid = threadIdx.x;            // 256 threads
    const float* xr = x + (size_t)n * C_DIM;
    const int c0 = tid * 8;

    float xv[8];
#pragma unroll
    for (int j = 0; j < 8; ++j) xv[j] = xr[c0 + j];

    float dots[9];
#pragma unroll
    for (int e = 0; e < 9; ++e) {
        const float* wr = (e < 8) ? (gate_w + (size_t)e * C_DIM) : sgate_w;
        float p = 0.f;
#pragma unroll
        for (int j = 0; j < 8; ++j) p += xv[j] * wr[c0 + j];
#pragma unroll
        for (int off = 32; off > 0; off >>= 1) p += __shfl_down(p, off);
        dots[e] = p;
    }

    __shared__ float red[4][9];
    const int wid = tid >> 6, lane = tid & 63;
    if (lane == 0) {
#pragma unroll
        for (int e = 0; e < 9; ++e) red[wid][e] = dots[e];
    }
    __syncthreads();
    if (tid == 0) {
        float l[9];
#pragma unroll
        for (int e = 0; e < 9; ++e)
            l[e] = red[0][e] + red[1][e] + red[2][e] + red[3][e];
        float mx = l[0];
#pragma unroll
        for (int e = 1; e < 8; ++e) mx = fmaxf(mx, l[e]);
        float p[8], s = 0.f;
#pragma unroll
        for (int e = 0; e < 8; ++e) { p[e] = expf(l[e] - mx); s += p[e]; }
        const float inv = 1.f / s;
#pragma unroll
        for (int e = 0; e < 8; ++e) p[e] *= inv;
        int i1 = 0;
#pragma unroll
        for (int e = 1; e < 8; ++e) if (p[e] > p[i1]) i1 = e;
        int i2 = (i1 == 0) ? 1 : 0;
#pragma unroll
        for (int e = 0; e < 8; ++e) if (e != i1 && p[e] > p[i2]) i2 = e;
        slotexp[2 * n]     = i1;  slotp[2 * n]     = p[i1];
        slotexp[2 * n + 1] = i2;  slotp[2 * n + 1] = p[i2];
        sig[n] = 1.f / (1.f + expf(-l[8]));
    }
}

// ---------------------------------------------------------------------------
// Stable scatter (unchanged, verified)
// ---------------------------------------------------------------------------
__global__ void scatter_kernel(const int* __restrict__ slotexp,
                               int* __restrict__ counts, int* __restrict__ bases,
                               int* __restrict__ pos_of, int* __restrict__ row_token)
{
    const int tid = threadIdx.x;            // 512 threads = 8 waves
    const int w = tid >> 6, lane = tid & 63;
    __shared__ int cnt[E_NUM], base[E_NUM];

    int run = 0;
    for (int s0 = 0; s0 < SLOTS; s0 += 64) {
        int e = slotexp[s0 + lane];
        unsigned long long m = __ballot(e == w);
        run += __popcll(m);
    }
    if (lane == 0) cnt[w] = run;
    __syncthreads();
    if (tid == 0) {
        int b = 0;
        for (int e = 0; e < E_NUM; ++e) { base[e] = b; b += cnt[e]; }
    }
    __syncthreads();
    run = 0;
    for (int s0 = 0; s0 < SLOTS; s0 += 64) {
        const int s = s0 + lane;
        const int e = slotexp[s];
        unsigned long long m = __ballot(e == w);
        if (e == w) {
            const unsigned long long lt = (lane == 0) ? 0ull : (~0ull >> (64 - lane));
            const int pos = base[w] + run + __popcll(m & lt);
            pos_of[s]      = pos;
            row_token[pos] = s >> 1;
        }
        run += __popcll(m);
    }
    if (lane == 0) { counts[w] = cnt[w]; bases[w] = base[w]; }
}

// ---------------------------------------------------------------------------
// f32->bf16 conversion for x + FC weights only (proj weights are converted
// inside the gemm_fc grid, overlapping the FC GEMM). 8192 elems/block,
// non-temporal (zero-reuse stream).
// ---------------------------------------------------------------------------
struct CvtArgs {
    const float* in[5];
    bf16*        out[5];
    int          cum[6];     // cumulative 8192-elem block counts, cum[0]=0
};

__global__ void cvt_all_kernel(CvtArgs a)
{
    int b = blockIdx.x;
    int s = 0;
#pragma unroll
    for (int k = 1; k < 5; ++k) s += (b >= a.cum[k]);
    const size_t base = (size_t)(b - a.cum[s]) * 8192;
    const float* in = a.in[s];
    bf16* out = a.out[s];
    const int t4 = threadIdx.x * 4;
    f32x4 v[8];
#pragma unroll
    for (int c = 0; c < 8; ++c)
        v[c] = __builtin_nontemporal_load((const f32x4*)(in + base + c * 1024 + t4));
#pragma unroll
    for (int c = 0; c < 8; ++c) {
        bf16x4 o;
#pragma unroll
        for (int j = 0; j < 4; ++j) o[j] = (bf16)v[c][j];
        __builtin_nontemporal_store(o, (bf16x4*)(out + base + c * 1024 + t4));
    }
}

// ---------------------------------------------------------------------------
// Gather token rows into per-expert-contiguous Xg.
// ---------------------------------------------------------------------------
__global__ void gather_kernel(const bf16* __restrict__ Xs,
                              const int* __restrict__ row_token,
                              bf16* __restrict__ Xg)
{
    const int pos = blockIdx.x;
    const int t   = row_token[pos];
    const bf16x8* s = (const bf16x8*)(Xs + (size_t)t * C_DIM);
    bf16x8*       d = (bf16x8*)(Xg + (size_t)pos * C_DIM);
    d[threadIdx.x] = s[threadIdx.x];
}

// ---------------------------------------------------------------------------
// Deep-pipelined NT GEMM body (round-15 verified: depth-4, 5 half-buffers,
// ONE barrier per half, reads hoisted, setprio; 201us FC / best total).
// ---------------------------------------------------------------------------
template<bool DUAL, int KSPLIT>
__device__ __forceinline__ void gemm_body(
    const bf16* __restrict__ A, int lda,
    const bf16* __restrict__ B1g, const bf16* __restrict__ B2g, size_t strideB,
    bf16* __restrict__ OUTh, bf16* __restrict__ OUTq, int ldo, size_t strideOut,
    int base, int cnt, int e, int yt, int nt, int kp, int K, char* lds)
{
    const int KT = (K / 64) / KSPLIT;
    const int H  = 2 * KT;                   // K=32 halves (>= 22)

    const int m0 = base + yt * 256;
    const int tid = threadIdx.x;
    const int w = tid >> 6, lane = tid & 63;

    // staging decode: dest linear (wave base + lane*16); content chunk at
    // slot (lane&7) of LDS row r' is (lane&7)^(r'&7), r'&7 == lane>>3
    const int l3  = lane >> 3;
    const int chS = (lane & 7) ^ l3;
    const int hiS = chS >> 2, ccS = chS & 3;
    const int rl  = w * 16 + 2 * l3 + hiS;   // tile row within 128-row group
    const size_t lda2 = (size_t)lda * 2, K2 = (size_t)K * 2;
    const size_t kpoff = (size_t)kp * KT * 128;

    const char* aSrc0 = (const char*)A + (size_t)(m0 + rl)       * lda2 + ccS * 16 + kpoff;
    const char* aSrc1 = (const char*)A + (size_t)(m0 + 128 + rl) * lda2 + ccS * 16 + kpoff;
    const bf16* B1 = B1g + (size_t)e * strideB;
    const char* bSrc0;
    const char* bSrc1;
    if constexpr (DUAL) {
        const bf16* B2 = B2g + (size_t)e * strideB;
        bSrc0 = (const char*)B1 + (size_t)(nt * 128 + rl) * K2 + ccS * 16 + kpoff;
        bSrc1 = (const char*)B2 + (size_t)(nt * 128 + rl) * K2 + ccS * 16 + kpoff;
    } else {
        bSrc0 = (const char*)B1 + (size_t)(nt * 256 + rl)       * K2 + ccS * 16 + kpoff;
        bSrc1 = (const char*)B1 + (size_t)(nt * 256 + 128 + rl) * K2 + ccS * 16 + kpoff;
    }
    char* ldsw = lds + w * 1024;             // wave-uniform LDS dest base

    auto issue = [&](int h, int buf) {       // 4 loads/wave per half
        const size_t ko = (size_t)(h >> 1) * 128 + (size_t)(h & 1) * 64;
        char* d = ldsw + buf * 32768;
        gload16(aSrc0 + ko, d);
        gload16(aSrc1 + ko, d + 8192);
        gload16(bSrc0 + ko, d + 16384);
        gload16(bSrc1 + ko, d + 24576);
    };

    // fragment read offsets (swizzled, constant across halves)
    const int wm = w >> 2, wn = w & 3;
    const int fr = lane & 15, fq = lane >> 4;
    const int chRd = (((fr & 1) << 2) | fq) ^ ((fr >> 1) & 7);
    uint32_t aOff[8], bOff[4];
#pragma unroll
    for (int m = 0; m < 8; ++m)
        aOff[m] = (uint32_t)((wm * 64 + m * 8 + (fr >> 1)) * 128 + chRd * 16);
#pragma unroll
    for (int n = 0; n < 4; ++n) {
        int rp;
        if constexpr (DUAL)
            rp = (n < 2) ? (wn * 16 + n * 8) : (64 + wn * 16 + (n - 2) * 8);
        else
            rp = wn * 32 + n * 8;
        rp += (fr >> 1);
        bOff[n] = (uint32_t)(16384 + rp * 128 + chRd * 16);
    }

    f32x4 acc[8][4] = {};

    auto compute_half = [&](int buf) {
        const char* LB = lds + buf * 32768;
        bf16x8 af[4], ag[4], bf[4];
#pragma unroll
        for (int n = 0; n < 4; ++n) bf[n] = *(const bf16x8*)(LB + bOff[n]);
#pragma unroll
        for (int m = 0; m < 4; ++m) af[m] = *(const bf16x8*)(LB + aOff[m]);
#pragma unroll
        for (int m = 0; m < 4; ++m) ag[m] = *(const bf16x8*)(LB + aOff[4 + m]);
        __builtin_amdgcn_s_setprio(1);
#pragma unroll
        for (int m = 0; m < 4; ++m)
#pragma unroll
            for (int n = 0; n < 4; ++n)
                acc[m][n] = mfma16(af[m], bf[n], acc[m][n]);
#pragma unroll
        for (int m = 0; m < 4; ++m)
#pragma unroll
            for (int n = 0; n < 4; ++n)
                acc[4 + m][n] = mfma16(ag[m], bf[n], acc[4 + m][n]);
        __builtin_amdgcn_s_setprio(0);
    };

    // prologue: 4 halves in flight (16 loads/wave)
    issue(0, 0); issue(1, 1); issue(2, 2); issue(3, 3);

    int cur = 0, wr = 4;                     // cur = h%5, wr = (h+4)%5
    for (int h = 0; h < H - 4; ++h) {
        VMCNT12();                           // half h landed (3 halves beyond)
        RAWBAR();                            // all waves: h resident, h-1 reads done
        issue(h + 4, wr);                    // reuses buffer (h-1)%5
        compute_half(cur);
        cur = (cur == 4) ? 0 : cur + 1;
        wr  = (wr  == 4) ? 0 : wr  + 1;
    }
    VMCNT12(); RAWBAR(); compute_half(cur); cur = (cur == 4) ? 0 : cur + 1;
    VMCNT8();  RAWBAR(); compute_half(cur); cur = (cur == 4) ? 0 : cur + 1;
    VMCNT4();  RAWBAR(); compute_half(cur); cur = (cur == 4) ? 0 : cur + 1;
    VMCNT0();  RAWBAR(); compute_half(cur);

    // epilogue. C/D: col = lane&15 (fr), row = fq*4 + j (m89)
    const int rb0 = m0 + wm * 128;
    const int rend = base + cnt;             // first row NOT owned by this range
#pragma unroll
    for (int m = 0; m < 8; ++m) {
#pragma unroll
        for (int j = 0; j < 4; ++j) {
            const int grow = rb0 + m * 16 + fq * 4 + j;
            if (grow >= rend) continue;      // tile tail overlaps next expert
            if constexpr (DUAL) {
#pragma unroll
                for (int n = 0; n < 2; ++n) {
                    const int gcol = nt * 128 + wn * 32 + n * 16 + fr;
                    const float h1 = acc[m][n][j];
                    const float h2 = acc[m][n + 2][j];
                    OUTh[(size_t)grow * ldo + gcol] =
                        (bf16)(h1 / (1.f + expf(-h1)) * h2);
                }
            } else {
                bf16* O = OUTq + (size_t)kp * strideOut;
#pragma unroll
                for (int n = 0; n < 4; ++n) {
                    const int gcol = nt * 256 + wn * 64 + n * 16 + fr;
                    O[(size_t)grow * ldo + gcol] = (bf16)acc[m][n][j];
                }
            }
        }
    }
}

// ---------------------------------------------------------------------------
// PROJ kernels: thin wrappers over gemm_body (round-11 grids, verified).
// ---------------------------------------------------------------------------
template<bool DUAL, bool GROUPED, int KSPLIT>
__global__ __launch_bounds__(512, 1)
void gemm8(const bf16* __restrict__ A, int lda,
           const bf16* __restrict__ B1g, const bf16* __restrict__ B2g,
           size_t strideB,
           bf16* __restrict__ OUTh, bf16* __restrict__ OUTq, int ldo,
           size_t strideOut,
           const int* __restrict__ bases, const int* __restrict__ counts,
           int K)
{
    __shared__ char lds[163840];
    int e, yt, nt, kp, base, cnt;
    if constexpr (GROUPED) {
        e = blockIdx.x; yt = blockIdx.y; nt = blockIdx.z; kp = 0;
        base = bases[e]; cnt = counts[e];
        if (yt * 256 >= cnt) return;
    } else {
        nt = blockIdx.x; yt = blockIdx.y; kp = (KSPLIT > 1) ? blockIdx.z : 0;
        e = 0; base = 0; cnt = N_TOK;
    }
    gemm_body<DUAL, KSPLIT>(A, lda, B1g, B2g, strideB, OUTh, OUTq, ldo,
                            strideOut, base, cnt, e, yt, nt, kp, K, lds);
}

// ---------------------------------------------------------------------------
// FC merged + proj-weight conversion fold:
//   ids [0,352):        sharedfc tiles (nt=id%44, yt=id/44)
//   ids [352,1760):     groupedfc tiles (e fastest, yt, nt)
//   ids [1760,3168):    eproj f32->bf16, 16384 elems each (1408 blocks)
//   ids [3168,3872):    sproj f32->bf16, 16384 elems each (704 blocks)
// The cvt blocks run on CUs left idle by the GEMM's ragged tail; stream
// order guarantees they complete before the PROJ launches consume W*.
// ---------------------------------------------------------------------------
#define FC0_TILES 352            // (N_TOK/256) * (F_SH/128)
#define FC_TILES  1760           // 352 + 1408
#define CVT_EP_BLKS 1408         // 8*2048*1408 / 16384
#define CVT_SP_BLKS 704          // 2048*5632 / 16384

__global__ __launch_bounds__(512, 1)
void gemm_fc(const bf16* __restrict__ Xs, const bf16* __restrict__ Xg,
             const bf16* __restrict__ Wsfc1, const bf16* __restrict__ Wsfc2,
             const bf16* __restrict__ Wefc1, const bf16* __restrict__ Wefc2,
             bf16* __restrict__ Hs, bf16* __restrict__ Hm,
             const float* __restrict__ eproj, const float* __restrict__ sproj,
             bf16* __restrict__ Weproj, bf16* __restrict__ Wsproj,
             const int* __restrict__ bases, const int* __restrict__ counts)
{
    __shared__ char lds[163840];
    const int id = blockIdx.x;
    if (id < FC0_TILES) {
        const int nt = id % 44, yt = id / 44;        // compile-time divisor
        gemm_body<true, 1>(Xs, C_DIM, Wsfc1, Wsfc2, 0, Hs, nullptr, F_SH, 0,
                           0, N_TOK, 0, yt, nt, 0, C_DIM, lds);
    } else if (id < FC_TILES) {
        const int lid = id - FC0_TILES;
        const int e = lid & 7, yt = (lid >> 3) & 15, nt = lid >> 7;
        const int base = bases[e], cnt = counts[e];
        if (yt * 256 >= cnt) return;
        gemm_body<true, 1>(Xg, C_DIM, Wefc1, Wefc2, (size_t)F_MOE * C_DIM,
                           Hm, nullptr, F_MOE, 0,
                           base, cnt, e, yt, nt, 0, C_DIM, lds);
    } else {
        // proj-weight conversion block: 16384 elems (512 thr x 32)
        const int cid = id - FC_TILES;
        const float* in;
        bf16* out;
        size_t base;
        if (cid < CVT_EP_BLKS) { in = eproj; out = Weproj; base = (size_t)cid * 16384; }
        else { in = sproj; out = Wsproj; base = (size_t)(cid - CVT_EP_BLKS) * 16384; }
        const int t4 = threadIdx.x * 4;
        f32x4 v[8];
#pragma unroll
        for (int c = 0; c < 8; ++c)
            v[c] = __builtin_nontemporal_load((const f32x4*)(in + base + c * 2048 + t4));
#pragma unroll
        for (int c = 0; c < 8; ++c) {
            bf16x4 o;
#pragma unroll
            for (int j = 0; j < 4; ++j) o[j] = (bf16)v[c][j];
            __builtin_nontemporal_store(o, (bf16x4*)(out + base + c * 2048 + t4));
        }
    }
}

// ---------------------------------------------------------------------------
// y[n] = sig[n]*(SP0+SP1+SP2+SP3)[n] + p0*EP[pos0] + p1*EP[pos1]
// ---------------------------------------------------------------------------
__global__ void combine_kernel(const bf16* __restrict__ SP,
                               const bf16* __restrict__ EP,
                               const int* __restrict__ pos_of,
                               const float* __restrict__ slotp,
                               const float* __restrict__ sig,
                               float* __restrict__ y)
{
    const int n  = blockIdx.x;
    const int p0 = pos_of[2 * n], p1 = pos_of[2 * n + 1];
    const float w0 = slotp[2 * n], w1 = slotp[2 * n + 1], sg = sig[n];
    const size_t PS = (size_t)N_TOK * C_DIM;
    const size_t cidx = (size_t)n * C_DIM + threadIdx.x * 8;

    bf16x8 s0 = *(const bf16x8*)(SP + cidx);
    bf16x8 s1 = *(const bf16x8*)(SP + cidx + PS);
    bf16x8 s2 = *(const bf16x8*)(SP + cidx + 2 * PS);
    bf16x8 s3 = *(const bf16x8*)(SP + cidx + 3 * PS);
    bf16x8 a0 = *(const bf16x8*)(EP + (size_t)p0 * C_DIM + threadIdx.x * 8);
    bf16x8 a1 = *(const bf16x8*)(EP + (size_t)p1 * C_DIM + threadIdx.x * 8);

    float out[8];
#pragma unroll
    for (int j = 0; j < 8; ++j) {
        const float ssum = (float)s0[j] + (float)s1[j] + (float)s2[j] + (float)s3[j];
        out[j] = sg * ssum + w0 * (float)a0[j] + w1 * (float)a1[j];
    }
    f32x4 o0, o1;
#pragma unroll
    for (int j = 0; j < 4; ++j) { o0[j] = out[j]; o1[j] = out[4 + j]; }
    *(f32x4*)(y + cidx)     = o0;
    *(f32x4*)(y + cidx + 4) = o1;
}

// ---------------------------------------------------------------------------
extern "C" void kernel_launch(void* const* d_in, const int* in_sizes, int n_in,
                              void* d_out, int out_size, void* d_ws, size_t ws_size,
                              hipStream_t stream)
{
    const float* x     = (const float*)d_in[0];
    const float* gatew = (const float*)d_in[1];
    const float* efc1  = (const float*)d_in[2];
    const float* efc2  = (const float*)d_in[3];
    const float* eproj = (const float*)d_in[4];
    const float* sfc1  = (const float*)d_in[5];
    const float* sfc2  = (const float*)d_in[6];
    const float* sproj = (const float*)d_in[7];
    const float* sgate = (const float*)d_in[8];
    float* y = (float*)d_out;

    char* w = (char*)d_ws;
    size_t off = 0;
    auto take = [&](size_t bytes) {
        char* p = w + off;
        off = (off + bytes + 255) & ~(size_t)255;
        return p;
    };
    int*   counts    = (int*)  take(E_NUM * 4);
    int*   bases     = (int*)  take(E_NUM * 4);
    int*   slotexp   = (int*)  take(SLOTS * 4);
    float* slotp     = (float*)take(SLOTS * 4);
    int*   pos_of    = (int*)  take(SLOTS * 4);
    int*   row_token = (int*)  take(PADROWS * 4);
    float* sig       = (float*)take(N_TOK * 4);
    bf16*  Xs        = (bf16*) take((size_t)N_TOK   * C_DIM * 2);
    bf16*  Xg        = (bf16*) take((size_t)PADROWS * C_DIM * 2);
    bf16*  Hs        = (bf16*) take((size_t)N_TOK   * F_SH  * 2);
    bf16*  Hm        = (bf16*) take((size_t)PADROWS * F_MOE * 2);
    bf16*  SP        = (bf16*) take((size_t)4 * N_TOK * C_DIM * 2);
    bf16*  EP        = (bf16*) take((size_t)PADROWS * C_DIM * 2);
    bf16*  Wefc1     = (bf16*) take((size_t)E_NUM * F_MOE * C_DIM * 2);
    bf16*  Wefc2     = (bf16*) take((size_t)E_NUM * F_MOE * C_DIM * 2);
    bf16*  Weproj    = (bf16*) take((size_t)E_NUM * C_DIM * F_MOE * 2);
    bf16*  Wsfc1     = (bf16*) take((size_t)F_SH * C_DIM * 2);
    bf16*  Wsfc2     = (bf16*) take((size_t)F_SH * C_DIM * 2);
    bf16*  Wsproj    = (bf16*) take((size_t)C_DIM * F_SH * 2);
    (void)ws_size; (void)in_sizes; (void)n_in; (void)out_size;

    // f32->bf16 for x + FC weights only (proj weights fold into gemm_fc)
    CvtArgs ca;
    const int nbx  = (N_TOK * C_DIM) / 8192;                 // 512
    const int nbe  = (E_NUM * F_MOE * C_DIM) / 8192;         // 2816
    const int nbs  = (F_SH * C_DIM) / 8192;                  // 1408
    ca.in[0] = x;     ca.out[0] = Xs;
    ca.in[1] = efc1;  ca.out[1] = Wefc1;
    ca.in[2] = efc2;  ca.out[2] = Wefc2;
    ca.in[3] = sfc1;  ca.out[3] = Wsfc1;
    ca.in[4] = sfc2;  ca.out[4] = Wsfc2;
    ca.cum[0] = 0;
    ca.cum[1] = nbx;
    ca.cum[2] = nbx + nbe;
    ca.cum[3] = nbx + 2 * nbe;
    ca.cum[4] = nbx + 2 * nbe + nbs;
    ca.cum[5] = nbx + 2 * nbe + 2 * nbs;
    cvt_all_kernel<<<ca.cum[5], 256, 0, stream>>>(ca);

    router_kernel<<<N_TOK, 256, 0, stream>>>(x, gatew, sgate, slotexp, slotp, sig);
    scatter_kernel<<<1, 512, 0, stream>>>(slotexp, counts, bases, pos_of, row_token);
    gather_kernel<<<SLOTS, 256, 0, stream>>>(Xs, row_token, Xg);

    // FC merged (352 shared + 1408 grouped tiles) + proj-weight cvt blocks
    gemm_fc<<<FC_TILES + CVT_EP_BLKS + CVT_SP_BLKS, 512, 0, stream>>>(
        Xs, Xg, Wsfc1, Wsfc2, Wefc1, Wefc2, Hs, Hm,
        eproj, sproj, Weproj, Wsproj, bases, counts);

    // shared proj, 4-way K-split bf16 partials: SP[p] = Hs @ sproj^T
    gemm8<false, false, 4><<<dim3(C_DIM / 256, N_TOK / 256, 4), 512, 0, stream>>>(
        Hs, F_SH, Wsproj, nullptr, 0, nullptr, SP, C_DIM, (size_t)N_TOK * C_DIM,
        nullptr, nullptr, F_SH);

    // MoE proj (grouped, e-fastest grid): EP = Hm @ proj_e^T (bf16)
    gemm8<false, true, 1><<<dim3(E_NUM, SLOTS / 256, C_DIM / 256), 512, 0, stream>>>(
        Hm, F_MOE, Weproj, nullptr, (size_t)C_DIM * F_MOE, nullptr, EP, C_DIM, 0,
        bases, counts, F_MOE);

    combine_kernel<<<N_TOK, 256, 0, stream>>>(SP, EP, pos_of, slotp, sig, y);
}

// Round 18
// 389.868 us; speedup vs baseline: 1.1170x; 1.0479x over previous
//
#include <hip/hip_runtime.h>
#include <hip/hip_bf16.h>
#include <math.h>
#include <stdint.h>

// Problem constants (B=2, T=1024 -> N=2048 tokens)
#define N_TOK   2048
#define C_DIM   2048
#define E_NUM   8
#define F_MOE   1408
#define F_SH    5632
#define SLOTS   4096            // N_TOK * TOPK
#define PADROWS 4608            // SLOTS + 512 slack for 256-row tile tails

typedef __bf16 bf16;
typedef __bf16 bf16x8 __attribute__((ext_vector_type(8)));
typedef __bf16 bf16x4 __attribute__((ext_vector_type(4)));
typedef float  f32x4  __attribute__((ext_vector_type(4)));

__device__ __forceinline__ f32x4 mfma16(bf16x8 a, bf16x8 b, f32x4 c) {
    return __builtin_amdgcn_mfma_f32_16x16x32_bf16(a, b, c, 0, 0, 0);
}
__device__ __forceinline__ void gload16(const void* g, void* l) {
    __builtin_amdgcn_global_load_lds(
        (const __attribute__((address_space(1))) void*)g,
        (__attribute__((address_space(3))) void*)l, 16, 0, 0);
}
#define RAWBAR()  asm volatile("s_barrier" ::: "memory")
#define VMCNT12() asm volatile("s_waitcnt vmcnt(12)" ::: "memory")
#define VMCNT8()  asm volatile("s_waitcnt vmcnt(8)" ::: "memory")
#define VMCNT4()  asm volatile("s_waitcnt vmcnt(4)" ::: "memory")
#define VMCNT0()  asm volatile("s_waitcnt vmcnt(0)" ::: "memory")

// ---------------------------------------------------------------------------
// Fused launch A: cvt-x blocks (ids [0,512), 8192 elems each) + router
// blocks (ids [512, 512+N_TOK)). Both paths use 256 threads; independent.
// ---------------------------------------------------------------------------
__global__ void cvtx_router_kernel(const float* __restrict__ x,
                                   bf16* __restrict__ Xs,
                                   const float* __restrict__ gate_w,
                                   const float* __restrict__ sgate_w,
                                   int* __restrict__ slotexp,
                                   float* __restrict__ slotp,
                                   float* __restrict__ sig)
{
    const int id = blockIdx.x;
    if (id < 512) {
        // x -> bf16, 8192 elems, non-temporal
        const size_t base = (size_t)id * 8192;
        const int t4 = threadIdx.x * 4;
        f32x4 v[8];
#pragma unroll
        for (int c = 0; c < 8; ++c)
            v[c] = __builtin_nontemporal_load((const f32x4*)(x + base + c * 1024 + t4));
#pragma unroll
        for (int c = 0; c < 8; ++c) {
            bf16x4 o;
#pragma unroll
            for (int j = 0; j < 4; ++j) o[j] = (bf16)v[c][j];
            __builtin_nontemporal_store(o, (bf16x4*)(Xs + base + c * 1024 + t4));
        }
        return;
    }
    // ---- router (verified body, n = id - 512) ----
    const int n   = id - 512;
    const int tid = threadIdx.x;
    const float* xr = x + (size_t)n * C_DIM;
    const int c0 = tid * 8;

    float xv[8];
#pragma unroll
    for (int j = 0; j < 8; ++j) xv[j] = xr[c0 + j];

    float dots[9];
#pragma unroll
    for (int e = 0; e < 9; ++e) {
        const float* wr = (e < 8) ? (gate_w + (size_t)e * C_DIM) : sgate_w;
        float p = 0.f;
#pragma unroll
        for (int j = 0; j < 8; ++j) p += xv[j] * wr[c0 + j];
#pragma unroll
        for (int off = 32; off > 0; off >>= 1) p += __shfl_down(p, off);
        dots[e] = p;
    }

    __shared__ float red[4][9];
    const int wid = tid >> 6, lane = tid & 63;
    if (lane == 0) {
#pragma unroll
        for (int e = 0; e < 9; ++e) red[wid][e] = dots[e];
    }
    __syncthreads();
    if (tid == 0) {
        float l[9];
#pragma unroll
        for (int e = 0; e < 9; ++e)
            l[e] = red[0][e] + red[1][e] + red[2][e] + red[3][e];
        float mx = l[0];
#pragma unroll
        for (int e = 1; e < 8; ++e) mx = fmaxf(mx, l[e]);
        float p[8], s = 0.f;
#pragma unroll
        for (int e = 0; e < 8; ++e) { p[e] = expf(l[e] - mx); s += p[e]; }
        const float inv = 1.f / s;
#pragma unroll
        for (int e = 0; e < 8; ++e) p[e] *= inv;
        int i1 = 0;
#pragma unroll
        for (int e = 1; e < 8; ++e) if (p[e] > p[i1]) i1 = e;
        int i2 = (i1 == 0) ? 1 : 0;
#pragma unroll
        for (int e = 0; e < 8; ++e) if (e != i1 && p[e] > p[i2]) i2 = e;
        slotexp[2 * n]     = i1;  slotp[2 * n]     = p[i1];
        slotexp[2 * n + 1] = i2;  slotp[2 * n + 1] = p[i2];
        sig[n] = 1.f / (1.f + expf(-l[8]));
    }
}

// ---------------------------------------------------------------------------
// Fused launch B: scatter (block 0, verified body) + FC-weight f32->bf16
// (ids [1, 4225): efc1 1408, efc2 1408, sfc1 704, sfc2 704 blocks of
// 16384 elems @ 512 threads). Scatter's serial block hides under the
// HBM-bound conversion stream.
// ---------------------------------------------------------------------------
#define CVT_EFC_BLKS 1408
#define CVT_SFC_BLKS 704

__global__ __launch_bounds__(512)
void scatter_cvt_kernel(const int* __restrict__ slotexp,
                        int* __restrict__ counts, int* __restrict__ bases,
                        int* __restrict__ pos_of, int* __restrict__ row_token,
                        const float* __restrict__ efc1, const float* __restrict__ efc2,
                        const float* __restrict__ sfc1, const float* __restrict__ sfc2,
                        bf16* __restrict__ Wefc1, bf16* __restrict__ Wefc2,
                        bf16* __restrict__ Wsfc1, bf16* __restrict__ Wsfc2)
{
    const int id = blockIdx.x;
    if (id == 0) {
        // ---- stable scatter (verified) ----
        const int tid = threadIdx.x;
        const int w = tid >> 6, lane = tid & 63;
        __shared__ int cnt[E_NUM], base[E_NUM];

        int run = 0;
        for (int s0 = 0; s0 < SLOTS; s0 += 64) {
            int e = slotexp[s0 + lane];
            unsigned long long m = __ballot(e == w);
            run += __popcll(m);
        }
        if (lane == 0) cnt[w] = run;
        __syncthreads();
        if (tid == 0) {
            int b = 0;
            for (int e = 0; e < E_NUM; ++e) { base[e] = b; b += cnt[e]; }
        }
        __syncthreads();
        run = 0;
        for (int s0 = 0; s0 < SLOTS; s0 += 64) {
            const int s = s0 + lane;
            const int e = slotexp[s];
            unsigned long long m = __ballot(e == w);
            if (e == w) {
                const unsigned long long lt = (lane == 0) ? 0ull : (~0ull >> (64 - lane));
                const int pos = base[w] + run + __popcll(m & lt);
                pos_of[s]      = pos;
                row_token[pos] = s >> 1;
            }
            run += __popcll(m);
        }
        if (lane == 0) { counts[w] = cnt[w]; bases[w] = base[w]; }
        return;
    }
    // ---- FC-weight conversion block: 16384 elems (512 thr x 32) ----
    int cid = id - 1;
    const float* in;
    bf16* out;
    if (cid < CVT_EFC_BLKS) { in = efc1; out = Wefc1; }
    else if (cid < 2 * CVT_EFC_BLKS) { in = efc2; out = Wefc2; cid -= CVT_EFC_BLKS; }
    else if (cid < 2 * CVT_EFC_BLKS + CVT_SFC_BLKS) { in = sfc1; out = Wsfc1; cid -= 2 * CVT_EFC_BLKS; }
    else { in = sfc2; out = Wsfc2; cid -= 2 * CVT_EFC_BLKS + CVT_SFC_BLKS; }
    const size_t base = (size_t)cid * 16384;
    const int t4 = threadIdx.x * 4;
    f32x4 v[8];
#pragma unroll
    for (int c = 0; c < 8; ++c)
        v[c] = __builtin_nontemporal_load((const f32x4*)(in + base + c * 2048 + t4));
#pragma unroll
    for (int c = 0; c < 8; ++c) {
        bf16x4 o;
#pragma unroll
        for (int j = 0; j < 4; ++j) o[j] = (bf16)v[c][j];
        __builtin_nontemporal_store(o, (bf16x4*)(out + base + c * 2048 + t4));
    }
}

// ---------------------------------------------------------------------------
// Gather token rows into per-expert-contiguous Xg.
// ---------------------------------------------------------------------------
__global__ void gather_kernel(const bf16* __restrict__ Xs,
                              const int* __restrict__ row_token,
                              bf16* __restrict__ Xg)
{
    const int pos = blockIdx.x;
    const int t   = row_token[pos];
    const bf16x8* s = (const bf16x8*)(Xs + (size_t)t * C_DIM);
    bf16x8*       d = (bf16x8*)(Xg + (size_t)pos * C_DIM);
    d[threadIdx.x] = s[threadIdx.x];
}

// ---------------------------------------------------------------------------
// Deep-pipelined NT GEMM body (round-15 verified: depth-4, 5 half-buffers,
// ONE barrier per half, reads hoisted, setprio).
// ---------------------------------------------------------------------------
template<bool DUAL, int KSPLIT>
__device__ __forceinline__ void gemm_body(
    const bf16* __restrict__ A, int lda,
    const bf16* __restrict__ B1g, const bf16* __restrict__ B2g, size_t strideB,
    bf16* __restrict__ OUTh, bf16* __restrict__ OUTq, int ldo, size_t strideOut,
    int base, int cnt, int e, int yt, int nt, int kp, int K, char* lds)
{
    const int KT = (K / 64) / KSPLIT;
    const int H  = 2 * KT;                   // K=32 halves (>= 22)

    const int m0 = base + yt * 256;
    const int tid = threadIdx.x;
    const int w = tid >> 6, lane = tid & 63;

    // staging decode: dest linear (wave base + lane*16); content chunk at
    // slot (lane&7) of LDS row r' is (lane&7)^(r'&7), r'&7 == lane>>3
    const int l3  = lane >> 3;
    const int chS = (lane & 7) ^ l3;
    const int hiS = chS >> 2, ccS = chS & 3;
    const int rl  = w * 16 + 2 * l3 + hiS;   // tile row within 128-row group
    const size_t lda2 = (size_t)lda * 2, K2 = (size_t)K * 2;
    const size_t kpoff = (size_t)kp * KT * 128;

    const char* aSrc0 = (const char*)A + (size_t)(m0 + rl)       * lda2 + ccS * 16 + kpoff;
    const char* aSrc1 = (const char*)A + (size_t)(m0 + 128 + rl) * lda2 + ccS * 16 + kpoff;
    const bf16* B1 = B1g + (size_t)e * strideB;
    const char* bSrc0;
    const char* bSrc1;
    if constexpr (DUAL) {
        const bf16* B2 = B2g + (size_t)e * strideB;
        bSrc0 = (const char*)B1 + (size_t)(nt * 128 + rl) * K2 + ccS * 16 + kpoff;
        bSrc1 = (const char*)B2 + (size_t)(nt * 128 + rl) * K2 + ccS * 16 + kpoff;
    } else {
        bSrc0 = (const char*)B1 + (size_t)(nt * 256 + rl)       * K2 + ccS * 16 + kpoff;
        bSrc1 = (const char*)B1 + (size_t)(nt * 256 + 128 + rl) * K2 + ccS * 16 + kpoff;
    }
    char* ldsw = lds + w * 1024;             // wave-uniform LDS dest base

    auto issue = [&](int h, int buf) {       // 4 loads/wave per half
        const size_t ko = (size_t)(h >> 1) * 128 + (size_t)(h & 1) * 64;
        char* d = ldsw + buf * 32768;
        gload16(aSrc0 + ko, d);
        gload16(aSrc1 + ko, d + 8192);
        gload16(bSrc0 + ko, d + 16384);
        gload16(bSrc1 + ko, d + 24576);
    };

    // fragment read offsets (swizzled, constant across halves)
    const int wm = w >> 2, wn = w & 3;
    const int fr = lane & 15, fq = lane >> 4;
    const int chRd = (((fr & 1) << 2) | fq) ^ ((fr >> 1) & 7);
    uint32_t aOff[8], bOff[4];
#pragma unroll
    for (int m = 0; m < 8; ++m)
        aOff[m] = (uint32_t)((wm * 64 + m * 8 + (fr >> 1)) * 128 + chRd * 16);
#pragma unroll
    for (int n = 0; n < 4; ++n) {
        int rp;
        if constexpr (DUAL)
            rp = (n < 2) ? (wn * 16 + n * 8) : (64 + wn * 16 + (n - 2) * 8);
        else
            rp = wn * 32 + n * 8;
        rp += (fr >> 1);
        bOff[n] = (uint32_t)(16384 + rp * 128 + chRd * 16);
    }

    f32x4 acc[8][4] = {};

    auto compute_half = [&](int buf) {
        const char* LB = lds + buf * 32768;
        bf16x8 af[4], ag[4], bf[4];
#pragma unroll
        for (int n = 0; n < 4; ++n) bf[n] = *(const bf16x8*)(LB + bOff[n]);
#pragma unroll
        for (int m = 0; m < 4; ++m) af[m] = *(const bf16x8*)(LB + aOff[m]);
#pragma unroll
        for (int m = 0; m < 4; ++m) ag[m] = *(const bf16x8*)(LB + aOff[4 + m]);
        __builtin_amdgcn_s_setprio(1);
#pragma unroll
        for (int m = 0; m < 4; ++m)
#pragma unroll
            for (int n = 0; n < 4; ++n)
                acc[m][n] = mfma16(af[m], bf[n], acc[m][n]);
#pragma unroll
        for (int m = 0; m < 4; ++m)
#pragma unroll
            for (int n = 0; n < 4; ++n)
                acc[4 + m][n] = mfma16(ag[m], bf[n], acc[4 + m][n]);
        __builtin_amdgcn_s_setprio(0);
    };

    // prologue: 4 halves in flight (16 loads/wave)
    issue(0, 0); issue(1, 1); issue(2, 2); issue(3, 3);

    int cur = 0, wr = 4;                     // cur = h%5, wr = (h+4)%5
    for (int h = 0; h < H - 4; ++h) {
        VMCNT12();                           // half h landed (3 halves beyond)
        RAWBAR();                            // all waves: h resident, h-1 reads done
        issue(h + 4, wr);                    // reuses buffer (h-1)%5
        compute_half(cur);
        cur = (cur == 4) ? 0 : cur + 1;
        wr  = (wr  == 4) ? 0 : wr  + 1;
    }
    VMCNT12(); RAWBAR(); compute_half(cur); cur = (cur == 4) ? 0 : cur + 1;
    VMCNT8();  RAWBAR(); compute_half(cur); cur = (cur == 4) ? 0 : cur + 1;
    VMCNT4();  RAWBAR(); compute_half(cur); cur = (cur == 4) ? 0 : cur + 1;
    VMCNT0();  RAWBAR(); compute_half(cur);

    // epilogue. C/D: col = lane&15 (fr), row = fq*4 + j (m89)
    const int rb0 = m0 + wm * 128;
    const int rend = base + cnt;             // first row NOT owned by this range
#pragma unroll
    for (int m = 0; m < 8; ++m) {
#pragma unroll
        for (int j = 0; j < 4; ++j) {
            const int grow = rb0 + m * 16 + fq * 4 + j;
            if (grow >= rend) continue;      // tile tail overlaps next expert
            if constexpr (DUAL) {
#pragma unroll
                for (int n = 0; n < 2; ++n) {
                    const int gcol = nt * 128 + wn * 32 + n * 16 + fr;
                    const float h1 = acc[m][n][j];
                    const float h2 = acc[m][n + 2][j];
                    OUTh[(size_t)grow * ldo + gcol] =
                        (bf16)(h1 / (1.f + expf(-h1)) * h2);
                }
            } else {
                bf16* O = OUTq + (size_t)kp * strideOut;
#pragma unroll
                for (int n = 0; n < 4; ++n) {
                    const int gcol = nt * 256 + wn * 64 + n * 16 + fr;
                    O[(size_t)grow * ldo + gcol] = (bf16)acc[m][n][j];
                }
            }
        }
    }
}

// ---------------------------------------------------------------------------
// FC merged + proj-weight conversion fold (round-17 verified):
//   ids [0,352):        sharedfc tiles (nt=id%44, yt=id/44)
//   ids [352,1760):     groupedfc tiles (e fastest, yt, nt)
//   ids [1760,3168):    eproj f32->bf16, 16384 elems each
//   ids [3168,3872):    sproj f32->bf16, 16384 elems each
// ---------------------------------------------------------------------------
#define FC0_TILES 352            // (N_TOK/256) * (F_SH/128)
#define FC_TILES  1760           // 352 + 1408
#define CVT_EP_BLKS 1408         // 8*2048*1408 / 16384
#define CVT_SP_BLKS 704          // 2048*5632 / 16384

__global__ __launch_bounds__(512, 1)
void gemm_fc(const bf16* __restrict__ Xs, const bf16* __restrict__ Xg,
             const bf16* __restrict__ Wsfc1, const bf16* __restrict__ Wsfc2,
             const bf16* __restrict__ Wefc1, const bf16* __restrict__ Wefc2,
             bf16* __restrict__ Hs, bf16* __restrict__ Hm,
             const float* __restrict__ eproj, const float* __restrict__ sproj,
             bf16* __restrict__ Weproj, bf16* __restrict__ Wsproj,
             const int* __restrict__ bases, const int* __restrict__ counts)
{
    __shared__ char lds[163840];
    const int id = blockIdx.x;
    if (id < FC0_TILES) {
        const int nt = id % 44, yt = id / 44;        // compile-time divisor
        gemm_body<true, 1>(Xs, C_DIM, Wsfc1, Wsfc2, 0, Hs, nullptr, F_SH, 0,
                           0, N_TOK, 0, yt, nt, 0, C_DIM, lds);
    } else if (id < FC_TILES) {
        const int lid = id - FC0_TILES;
        const int e = lid & 7, yt = (lid >> 3) & 15, nt = lid >> 7;
        const int base = bases[e], cnt = counts[e];
        if (yt * 256 >= cnt) return;
        gemm_body<true, 1>(Xg, C_DIM, Wefc1, Wefc2, (size_t)F_MOE * C_DIM,
                           Hm, nullptr, F_MOE, 0,
                           base, cnt, e, yt, nt, 0, C_DIM, lds);
    } else {
        // proj-weight conversion block: 16384 elems (512 thr x 32)
        const int cid = id - FC_TILES;
        const float* in;
        bf16* out;
        size_t base;
        if (cid < CVT_EP_BLKS) { in = eproj; out = Weproj; base = (size_t)cid * 16384; }
        else { in = sproj; out = Wsproj; base = (size_t)(cid - CVT_EP_BLKS) * 16384; }
        const int t4 = threadIdx.x * 4;
        f32x4 v[8];
#pragma unroll
        for (int c = 0; c < 8; ++c)
            v[c] = __builtin_nontemporal_load((const f32x4*)(in + base + c * 2048 + t4));
#pragma unroll
        for (int c = 0; c < 8; ++c) {
            bf16x4 o;
#pragma unroll
            for (int j = 0; j < 4; ++j) o[j] = (bf16)v[c][j];
            __builtin_nontemporal_store(o, (bf16x4*)(out + base + c * 2048 + t4));
        }
    }
}

// ---------------------------------------------------------------------------
// PROJ merged (this round): sharedproj KSPLIT=4 (ids [0,256): nt=id&7,
// yt=(id>>3)&7, kp=id>>6 -- identical order to the old dim3 grid) +
// groupedproj (ids [256,1280): e fastest, yt, nt -- identical to old grid).
// Both branches compile-time specialized (gemm_fc precedent; rule #20 safe).
// ---------------------------------------------------------------------------
#define PROJ0_TILES 256          // 8 nt * 8 yt * 4 kp

__global__ __launch_bounds__(512, 1)
void gemm_proj(const bf16* __restrict__ Hs, const bf16* __restrict__ Hm,
               const bf16* __restrict__ Wsproj, const bf16* __restrict__ Weproj,
               bf16* __restrict__ SP, bf16* __restrict__ EP,
               const int* __restrict__ bases, const int* __restrict__ counts)
{
    __shared__ char lds[163840];
    const int id = blockIdx.x;
    if (id < PROJ0_TILES) {
        const int nt = id & 7, yt = (id >> 3) & 7, kp = id >> 6;
        gemm_body<false, 4>(Hs, F_SH, Wsproj, nullptr, 0, nullptr, SP, C_DIM,
                            (size_t)N_TOK * C_DIM,
                            0, N_TOK, 0, yt, nt, kp, F_SH, lds);
    } else {
        const int lid = id - PROJ0_TILES;
        const int e = lid & 7, yt = (lid >> 3) & 15, nt = lid >> 7;
        const int base = bases[e], cnt = counts[e];
        if (yt * 256 >= cnt) return;
        gemm_body<false, 1>(Hm, F_MOE, Weproj, nullptr, (size_t)C_DIM * F_MOE,
                            nullptr, EP, C_DIM, 0,
                            base, cnt, e, yt, nt, 0, F_MOE, lds);
    }
}

// ---------------------------------------------------------------------------
// y[n] = sig[n]*(SP0+SP1+SP2+SP3)[n] + p0*EP[pos0] + p1*EP[pos1]
// ---------------------------------------------------------------------------
__global__ void combine_kernel(const bf16* __restrict__ SP,
                               const bf16* __restrict__ EP,
                               const int* __restrict__ pos_of,
                               const float* __restrict__ slotp,
                               const float* __restrict__ sig,
                               float* __restrict__ y)
{
    const int n  = blockIdx.x;
    const int p0 = pos_of[2 * n], p1 = pos_of[2 * n + 1];
    const float w0 = slotp[2 * n], w1 = slotp[2 * n + 1], sg = sig[n];
    const size_t PS = (size_t)N_TOK * C_DIM;
    const size_t cidx = (size_t)n * C_DIM + threadIdx.x * 8;

    bf16x8 s0 = *(const bf16x8*)(SP + cidx);
    bf16x8 s1 = *(const bf16x8*)(SP + cidx + PS);
    bf16x8 s2 = *(const bf16x8*)(SP + cidx + 2 * PS);
    bf16x8 s3 = *(const bf16x8*)(SP + cidx + 3 * PS);
    bf16x8 a0 = *(const bf16x8*)(EP + (size_t)p0 * C_DIM + threadIdx.x * 8);
    bf16x8 a1 = *(const bf16x8*)(EP + (size_t)p1 * C_DIM + threadIdx.x * 8);

    float out[8];
#pragma unroll
    for (int j = 0; j < 8; ++j) {
        const float ssum = (float)s0[j] + (float)s1[j] + (float)s2[j] + (float)s3[j];
        out[j] = sg * ssum + w0 * (float)a0[j] + w1 * (float)a1[j];
    }
    f32x4 o0, o1;
#pragma unroll
    for (int j = 0; j < 4; ++j) { o0[j] = out[j]; o1[j] = out[4 + j]; }
    *(f32x4*)(y + cidx)     = o0;
    *(f32x4*)(y + cidx + 4) = o1;
}

// ---------------------------------------------------------------------------
extern "C" void kernel_launch(void* const* d_in, const int* in_sizes, int n_in,
                              void* d_out, int out_size, void* d_ws, size_t ws_size,
                              hipStream_t stream)
{
    const float* x     = (const float*)d_in[0];
    const float* gatew = (const float*)d_in[1];
    const float* efc1  = (const float*)d_in[2];
    const float* efc2  = (const float*)d_in[3];
    const float* eproj = (const float*)d_in[4];
    const float* sfc1  = (const float*)d_in[5];
    const float* sfc2  = (const float*)d_in[6];
    const float* sproj = (const float*)d_in[7];
    const float* sgate = (const float*)d_in[8];
    float* y = (float*)d_out;

    char* w = (char*)d_ws;
    size_t off = 0;
    auto take = [&](size_t bytes) {
        char* p = w + off;
        off = (off + bytes + 255) & ~(size_t)255;
        return p;
    };
    int*   counts    = (int*)  take(E_NUM * 4);
    int*   bases     = (int*)  take(E_NUM * 4);
    int*   slotexp   = (int*)  take(SLOTS * 4);
    float* slotp     = (float*)take(SLOTS * 4);
    int*   pos_of    = (int*)  take(SLOTS * 4);
    int*   row_token = (int*)  take(PADROWS * 4);
    float* sig       = (float*)take(N_TOK * 4);
    bf16*  Xs        = (bf16*) take((size_t)N_TOK   * C_DIM * 2);
    bf16*  Xg        = (bf16*) take((size_t)PADROWS * C_DIM * 2);
    bf16*  Hs        = (bf16*) take((size_t)N_TOK   * F_SH  * 2);
    bf16*  Hm        = (bf16*) take((size_t)PADROWS * F_MOE * 2);
    bf16*  SP        = (bf16*) take((size_t)4 * N_TOK * C_DIM * 2);
    bf16*  EP        = (bf16*) take((size_t)PADROWS * C_DIM * 2);
    bf16*  Wefc1     = (bf16*) take((size_t)E_NUM * F_MOE * C_DIM * 2);
    bf16*  Wefc2     = (bf16*) take((size_t)E_NUM * F_MOE * C_DIM * 2);
    bf16*  Weproj    = (bf16*) take((size_t)E_NUM * C_DIM * F_MOE * 2);
    bf16*  Wsfc1     = (bf16*) take((size_t)F_SH * C_DIM * 2);
    bf16*  Wsfc2     = (bf16*) take((size_t)F_SH * C_DIM * 2);
    bf16*  Wsproj    = (bf16*) take((size_t)C_DIM * F_SH * 2);
    (void)ws_size; (void)in_sizes; (void)n_in; (void)out_size;

    // launch A: cvt-x (512 blocks) + router (2048 blocks)
    cvtx_router_kernel<<<512 + N_TOK, 256, 0, stream>>>(
        x, Xs, gatew, sgate, slotexp, slotp, sig);

    // launch B: scatter (block 0) + FC-weight conversions (4224 blocks)
    scatter_cvt_kernel<<<1 + 2 * CVT_EFC_BLKS + 2 * CVT_SFC_BLKS, 512, 0, stream>>>(
        slotexp, counts, bases, pos_of, row_token,
        efc1, efc2, sfc1, sfc2, Wefc1, Wefc2, Wsfc1, Wsfc2);

    gather_kernel<<<SLOTS, 256, 0, stream>>>(Xs, row_token, Xg);

    // FC merged (352 shared + 1408 grouped tiles) + proj-weight cvt blocks
    gemm_fc<<<FC_TILES + CVT_EP_BLKS + CVT_SP_BLKS, 512, 0, stream>>>(
        Xs, Xg, Wsfc1, Wsfc2, Wefc1, Wefc2, Hs, Hm,
        eproj, sproj, Weproj, Wsproj, bases, counts);

    // PROJ merged: sharedproj (256 tiles, KSPLIT=4) + groupedproj (1024 tiles)
    gemm_proj<<<PROJ0_TILES + E_NUM * (SLOTS / 256) * (C_DIM / 256), 512, 0, stream>>>(
        Hs, Hm, Wsproj, Weproj, SP, EP, bases, counts);

    combine_kernel<<<N_TOK, 256, 0, stream>>>(SP, EP, pos_of, slotp, sig, y);
}